// Round 6
// baseline (153.025 us; speedup 1.0000x reference)
//
#include <hip/hip_runtime.h>

#define NGRID 257
#define LDS_PITCH 260                      // halfs per row; 520 B stride = 65 x 8B
#define LDS_BYTES (LDS_PITCH * NGRID * 2)  // 133640 B < 160 KiB
#define BLOCK 1024
#define GRID 32                            // DIAGNOSTIC: 8x work/CU -> kernel MUST surface in rocprof
#define OUTER 64                           // 2 points/iter: 32*1024*128 == 4,194,304 exactly

typedef _Float16 half2_t __attribute__((ext_vector_type(2)));
typedef _Float16 half4_t __attribute__((ext_vector_type(4)));
typedef float    f32x2  __attribute__((ext_vector_type(2)));

// 4-byte-aligned float4 view (coe rows have odd stride 257)
struct __attribute__((packed, aligned(4))) f4u { float x, y, z, w; };

__device__ __forceinline__ half2_t pack2(float a, float b) {
    return __builtin_bit_cast(half2_t, __builtin_amdgcn_cvt_pkrtz(a, b));
}

// Per-grid-index Lagrange denominator reciprocal: d(j) for j = g mod 4.
__device__ __forceinline__ float rowscale(int r) {
    return (r & 1) ? (-1.0f / 6.0f) : ((r & 2) ? 0.25f : (1.0f / 24.0f));
}

// Packed numerator basis for both dims of one point (denoms folded into LDS coe).
__device__ __forceinline__ void nbasis(f32x2 fr, f32x2 n[5]) {
    f32x2 f0 = fr * 4.0f;
    f32x2 f1 = f0 - 1.0f;
    f32x2 f2 = f0 - 2.0f;
    f32x2 f3 = f1 - 2.0f;
    f32x2 f4 = f0 - 4.0f;
    f32x2 p01 = f0 * f1;
    f32x2 p12 = f1 * f2;
    f32x2 p23 = f2 * f3;
    f32x2 p34 = f3 * f4;
    n[0] = p12 * p34;
    n[1] = (f0 * f2) * p34;
    n[2] = p01 * p34;
    n[3] = p01 * (f2 * f4);
    n[4] = p01 * p23;
}

// TWO points per call: 12 DS gathers issued back-to-back, two independent
// dot chains (R3 body, unchanged -- this round varies ONLY grid geometry).
__device__ __forceinline__ float2 eval2(const _Float16* __restrict__ lds,
                                        float xa0, float xa1,
                                        float xb0, float xb1) {
    float ua0 = xa0 * 64.0f, ua1 = xa1 * 64.0f;
    float ub0 = xb0 * 64.0f, ub1 = xb1 * 64.0f;
    int ia0 = (int)ua0, ia1 = (int)ua1;
    int ib0 = (int)ub0, ib1 = (int)ub1;
    f32x2 frA = { __builtin_amdgcn_fractf(ua0), __builtin_amdgcn_fractf(ua1) };
    f32x2 frB = { __builtin_amdgcn_fractf(ub0), __builtin_amdgcn_fractf(ub1) };

    const _Float16* baseA  = lds + (ia0 * 4) * LDS_PITCH + ia1 * 4;
    const _Float16* baseA2 = baseA + 2 * LDS_PITCH;
    const _Float16* baseB  = lds + (ib0 * 4) * LDS_PITCH + ib1 * 4;
    const _Float16* baseB2 = baseB + 2 * LDS_PITCH;

    // ---- 12 gathers, program-order adjacent ----
    half4_t la0 = *(const half4_t*)(baseA);
    half4_t la1 = *(const half4_t*)(baseA + LDS_PITCH);
    half4_t la2 = *(const half4_t*)(baseA2);
    half4_t la3 = *(const half4_t*)(baseA2 + LDS_PITCH);
    half4_t la4 = *(const half4_t*)(baseA2 + 2 * LDS_PITCH);
    half2_t ha0 = *(const half2_t*)(baseA + 4);
    half2_t ha1 = *(const half2_t*)(baseA + LDS_PITCH + 4);
    half2_t ha2 = *(const half2_t*)(baseA2 + 4);
    half2_t ha3 = *(const half2_t*)(baseA2 + LDS_PITCH + 4);
    half2_t ha4 = *(const half2_t*)(baseA2 + 2 * LDS_PITCH + 4);

    half4_t lb0 = *(const half4_t*)(baseB);
    half4_t lb1 = *(const half4_t*)(baseB + LDS_PITCH);
    half4_t lb2 = *(const half4_t*)(baseB2);
    half4_t lb3 = *(const half4_t*)(baseB2 + LDS_PITCH);
    half4_t lb4 = *(const half4_t*)(baseB2 + 2 * LDS_PITCH);
    half2_t hb0 = *(const half2_t*)(baseB + 4);
    half2_t hb1 = *(const half2_t*)(baseB + LDS_PITCH + 4);
    half2_t hb2 = *(const half2_t*)(baseB2 + 4);
    half2_t hb3 = *(const half2_t*)(baseB2 + LDS_PITCH + 4);
    half2_t hb4 = *(const half2_t*)(baseB2 + 2 * LDS_PITCH + 4);

    // ---- bases for both points (VALU overlaps DS latency) ----
    f32x2 nA[5], nB[5];
    nbasis(frA, nA);
    nbasis(frB, nB);
    half2_t qA01 = pack2(nA[0][1], nA[1][1]);
    half2_t qA23 = pack2(nA[2][1], nA[3][1]);
    float   bA4  = nA[4][1];
    half2_t qB01 = pack2(nB[0][1], nB[1][1]);
    half2_t qB23 = pack2(nB[2][1], nB[3][1]);
    float   bB4  = nB[4][1];

    half4_t loA[5] = { la0, la1, la2, la3, la4 };
    half2_t hiA[5] = { ha0, ha1, ha2, ha3, ha4 };
    half4_t loB[5] = { lb0, lb1, lb2, lb3, lb4 };
    half2_t hiB[5] = { hb0, hb1, hb2, hb3, hb4 };

    float rdA[5], rdB[5];
#pragma unroll
    for (int i = 0; i < 5; ++i) {
        half2_t xy = __builtin_shufflevector(loA[i], loA[i], 0, 1);
        half2_t zw = __builtin_shufflevector(loA[i], loA[i], 2, 3);
        float r = (float)hiA[i][0] * bA4;
        r = __builtin_amdgcn_fdot2(zw, qA23, r, false);
        r = __builtin_amdgcn_fdot2(xy, qA01, r, false);
        rdA[i] = r;
    }
#pragma unroll
    for (int i = 0; i < 5; ++i) {
        half2_t xy = __builtin_shufflevector(loB[i], loB[i], 0, 1);
        half2_t zw = __builtin_shufflevector(loB[i], loB[i], 2, 3);
        float r = (float)hiB[i][0] * bB4;
        r = __builtin_amdgcn_fdot2(zw, qB23, r, false);
        r = __builtin_amdgcn_fdot2(xy, qB01, r, false);
        rdB[i] = r;
    }

    float accA = nA[4][0] * rdA[4];
    accA = fmaf(nA[0][0], rdA[0], accA);
    accA = fmaf(nA[2][0], rdA[2], accA);
    float accA2 = nA[1][0] * rdA[1];
    accA2 = fmaf(nA[3][0], rdA[3], accA2);

    float accB = nB[4][0] * rdB[4];
    accB = fmaf(nB[0][0], rdB[0], accB);
    accB = fmaf(nB[2][0], rdB[2], accB);
    float accB2 = nB[1][0] * rdB[1];
    accB2 = fmaf(nB[3][0], rdB[3], accB2);

    float2 r;
    r.x = accA + accA2;
    r.y = accB + accB2;
    return r;
}

__launch_bounds__(BLOCK, 4)   // VGPR<=128; single 133KB-LDS block
__global__ void lagrange_kernel(const float* __restrict__ inputs,
                                const float* __restrict__ coe,
                                float* __restrict__ out,
                                int npts) {
    extern __shared__ _Float16 lds[];
    const int t = threadIdx.x;
    const int tid = blockIdx.x * BLOCK + t;
    const int stride = GRID * BLOCK;                         // 32768
    const float2* __restrict__ in2 = (const float2*)inputs;  // 1 point / float2
    (void)npts;   // npts == GRID*BLOCK*2*OUTER exactly -> no bounds checks

    // ---- input prefetch issued before staging (R5 structure) ----
    float2 a0 = in2[tid];
    float2 a1 = in2[tid + stride];
    float2 a2 = in2[tid + 2 * stride];
    float2 b0 = in2[tid + OUTER * stride];
    float2 b1 = in2[tid + (OUTER + 1) * stride];
    float2 b2 = in2[tid + (OUTER + 2) * stride];

    // ---- staging: loads batched ahead of converts (R5), denom folding (R2) ----
    float tail_col = 0.0f;
    if (t < NGRID) tail_col = coe[t * NGRID + 256];
    f4u qr;
    if (t < 64) qr = *(const f4u*)(coe + 256 * NGRID + (t << 2));
    f4u q[16];
#pragma unroll
    for (int k = 0; k < 16; ++k) {
        int g = t + k * BLOCK;          // 0..16383: rows 0..255 complete
        q[k] = *(const f4u*)(coe + (g >> 6) * NGRID + ((g & 63) << 2));
    }
#pragma unroll
    for (int k = 0; k < 16; ++k) {
        int g = t + k * BLOCK;
        int r = g >> 6;
        int c4 = (g & 63) << 2;
        float rs = rowscale(r);
        half4_t h = { (_Float16)(q[k].x * (rs * (1.0f / 24.0f))),
                      (_Float16)(q[k].y * (rs * (-1.0f / 6.0f))),
                      (_Float16)(q[k].z * (rs * 0.25f)),
                      (_Float16)(q[k].w * (rs * (-1.0f / 6.0f))) };
        *(half4_t*)(lds + r * LDS_PITCH + c4) = h;
    }
    if (t < 64) {                       // row 256 (scale 1/24), quads 0..63
        const float rs = 1.0f / 24.0f;
        half4_t h = { (_Float16)(qr.x * (rs * (1.0f / 24.0f))),
                      (_Float16)(qr.y * (rs * (-1.0f / 6.0f))),
                      (_Float16)(qr.z * (rs * 0.25f)),
                      (_Float16)(qr.w * (rs * (-1.0f / 6.0f))) };
        *(half4_t*)(lds + 256 * LDS_PITCH + (t << 2)) = h;
    }
    if (t < NGRID) {                    // column 256 (scale 1/24), all 257 rows
        float rs = rowscale(t);
        lds[t * LDS_PITCH + 256] = (_Float16)(tail_col * (rs * (1.0f / 24.0f)));
    }
    __syncthreads();

    // Two point streams (k and k+OUTER), 3-deep input prefetch each.
    // unroll 2 (not full): 64 iters fully unrolled would blow the I-cache.
#pragma unroll 2
    for (int k = 0; k < OUTER; ++k) {
        float2 a3, b3;
        if (k + 3 < OUTER) {
            a3 = in2[tid + (k + 3) * stride];
            b3 = in2[tid + (k + OUTER + 3) * stride];
        }
        float2 r = eval2(lds, a0.x, a0.y, b0.x, b0.y);
        __builtin_nontemporal_store(r.x, &out[tid + k * stride]);
        __builtin_nontemporal_store(r.y, &out[tid + (k + OUTER) * stride]);
        a0 = a1; a1 = a2; a2 = a3;
        b0 = b1; b1 = b2; b2 = b3;
    }
}

extern "C" void kernel_launch(void* const* d_in, const int* in_sizes, int n_in,
                              void* d_out, int out_size, void* d_ws, size_t ws_size,
                              hipStream_t stream) {
    const float* inputs = (const float*)d_in[0];   // (2048,2048,2) f32
    const float* coe    = (const float*)d_in[1];   // (257,257) f32
    float* out = (float*)d_out;                    // (2048,2048) f32
    int npts = out_size;                           // 4,194,304

    (void)hipFuncSetAttribute((const void*)lagrange_kernel,
                              hipFuncAttributeMaxDynamicSharedMemorySize,
                              LDS_BYTES);

    dim3 grid(GRID), block(BLOCK);   // DIAGNOSTIC: 32 blocks on 256 CUs, 8x work each
    hipLaunchKernelGGL(lagrange_kernel, grid, block, LDS_BYTES, stream,
                       inputs, coe, out, npts);
}

// Round 7
// 91.981 us; speedup vs baseline: 1.6637x; 1.6637x over previous
//
#include <hip/hip_runtime.h>

#define NGRID 257
#define BLOCK 1024
#define GRID 256
#define OUTER 8        // 2 points/iter: 256*1024*16 == 4,194,304 exactly

// ---------------- LDS layout (163,604 B of 163,840) ----------------
// MAIN: rows 0..255 x cols 0..255, f16, pitch 256 halves (512 B). b64 row reads
//       at byte 512*r + 8*i1: pair-slot = i1 mod 16 (uniform-16, random floor).
// S1  : row 256, cols 0..255 (512 B) -- j=4 b64 when i0==63 (branchless cndmask).
// T   : transposed 5th-columns, dword-packed: T[c1] = col (4*c1+4), row-pairs
//       (2d, 2d+1), d = 0..124. Stride 125 dwords == 29 (mod 32), gcd(29,32)=1
//       -> b32 slot = (29*c1 + 2*i0 + k) uniform over ALL 32 banks. Replaces the
//       5 even-bank-only b32 gathers (7.7 passes) with 3 full-spread b32s (4.7).
// S2  : col 256, rows 248..256 (9 halves) -- (i1==63, i0>=62) fallback.
#define OFF1_H  65536              // S1 at byte 131072
#define T_DW    32896              // T  at byte 131584 (dword index)
#define S2_H    81792              // S2 at byte 163584
#define LDS_BYTES 163616

typedef _Float16 half2_t __attribute__((ext_vector_type(2)));
typedef _Float16 half4_t __attribute__((ext_vector_type(4)));
typedef float    f32x2  __attribute__((ext_vector_type(2)));

struct __attribute__((packed, aligned(4))) f4u { float x, y, z, w; };

__device__ __forceinline__ half2_t pack2(float a, float b) {
    return __builtin_bit_cast(half2_t, __builtin_amdgcn_cvt_pkrtz(a, b));
}

// Lagrange denominator reciprocal for grid index r (mod 4); folded at staging.
__device__ __forceinline__ float rowscale(int r) {
    return (r & 1) ? (-1.0f / 6.0f) : ((r & 2) ? 0.25f : (1.0f / 24.0f));
}

// Packed numerator basis for both dims of one point (denoms folded into LDS coe).
__device__ __forceinline__ void nbasis(f32x2 fr, f32x2 n[5]) {
    f32x2 f0 = fr * 4.0f;
    f32x2 f1 = f0 - 1.0f;
    f32x2 f2 = f0 - 2.0f;
    f32x2 f3 = f1 - 2.0f;
    f32x2 f4 = f0 - 4.0f;
    f32x2 p01 = f0 * f1;
    f32x2 p12 = f1 * f2;
    f32x2 p23 = f2 * f3;
    f32x2 p34 = f3 * f4;
    n[0] = p12 * p34;
    n[1] = (f0 * f2) * p34;
    n[2] = p01 * p34;
    n[3] = p01 * (f2 * f4);
    n[4] = p01 * p23;
}

// One point: 5 b64 row reads (main/S1) + 3 full-bank-spread b32 T reads.
// Rare lanes (i0 >= 62: 3.1%) divergently re-fetch the 5th column via 5
// ds_read_u16 (1-2 active lanes -> ~1 cycle each).
__device__ __forceinline__ float eval_pt(const _Float16* __restrict__ lds,
                                         float x0, float x1) {
    float u0 = x0 * 64.0f, u1 = x1 * 64.0f;
    int i0 = (int)u0;
    int i1 = (int)u1;
    f32x2 fr = { __builtin_amdgcn_fractf(u0), __builtin_amdgcn_fractf(u1) };

    // ---- issue all gathers up front ----
    const _Float16* mb = lds + (i0 << 10) + (i1 << 2);   // row 4*i0, cols 4*i1..
    half4_t l0 = *(const half4_t*)(mb);
    half4_t l1 = *(const half4_t*)(mb + 256);
    half4_t l2 = *(const half4_t*)(mb + 512);
    half4_t l3 = *(const half4_t*)(mb + 768);
    const _Float16* p4 = (i0 < 63) ? (mb + 1024) : (lds + OFF1_H + (i1 << 2));
    half4_t l4 = *(const half4_t*)(p4);

    // T reads: unconditional (i0 >= 62 reads in-bounds junk, overwritten below)
    const unsigned* tp = (const unsigned*)lds + T_DW + 125 * i1 + 2 * i0;
    unsigned D0 = tp[0], D1 = tp[1], D2 = tp[2];

    // ---- bases (VALU overlaps DS latency) ----
    f32x2 n[5];
    nbasis(fr, n);
    half2_t q01 = pack2(n[0][1], n[1][1]);   // col weights (dim 1) for b64 dots
    half2_t q23 = pack2(n[2][1], n[3][1]);
    half2_t pA  = pack2(n[0][0], n[1][0]);   // row weights (dim 0) for T dot
    half2_t pB  = pack2(n[2][0], n[3][0]);

    half2_t C01 = __builtin_bit_cast(half2_t, D0);
    half2_t C23 = __builtin_bit_cast(half2_t, D1);
    _Float16 C4 = __builtin_bit_cast(half2_t, D2)[0];
    if (__builtin_expect(i0 >= 62, 0)) {     // rows 248..256 not in T
        _Float16 v[5];
#pragma unroll
        for (int i = 0; i < 5; ++i) {
            int r = 4 * i0 + i;
            const _Float16* p;
            if (i1 < 63) p = (r < 256) ? (lds + (r << 8) + (i1 << 2) + 4)
                                       : (lds + OFF1_H + (i1 << 2) + 4);
            else         p = lds + S2_H + (r - 248);
            v[i] = *p;
        }
        C01 = half2_t{ v[0], v[1] };
        C23 = half2_t{ v[2], v[3] };
        C4  = v[4];
    }

    // ---- 5th-column dot (row weights), then 4-col dots (col weights) ----
    float cs = (float)C4 * n[4][0];
    cs = __builtin_amdgcn_fdot2(C23, pB, cs, false);
    cs = __builtin_amdgcn_fdot2(C01, pA, cs, false);

    half4_t lo[5] = { l0, l1, l2, l3, l4 };
    float rd[5];
#pragma unroll
    for (int i = 0; i < 5; ++i) {
        half2_t xy = __builtin_shufflevector(lo[i], lo[i], 0, 1);
        half2_t zw = __builtin_shufflevector(lo[i], lo[i], 2, 3);
        rd[i] = __builtin_amdgcn_fdot2(xy, q01,
                __builtin_amdgcn_fdot2(zw, q23, 0.0f, false), false);
    }
    // dual-chain accumulation
    float accA = n[4][0] * rd[4];
    accA = fmaf(n[0][0], rd[0], accA);
    accA = fmaf(n[2][0], rd[2], accA);
    float accB = n[4][1] * cs;               // 5th-column contribution
    accB = fmaf(n[1][0], rd[1], accB);
    accB = fmaf(n[3][0], rd[3], accB);
    return accA + accB;
}

__launch_bounds__(BLOCK, 4)   // VGPR<=128; single 160KB-LDS block, 16 waves/CU
__global__ void lagrange_kernel(const float* __restrict__ inputs,
                                const float* __restrict__ coe,
                                float* __restrict__ out,
                                int npts) {
    extern __shared__ _Float16 lds[];
    const int t = threadIdx.x;
    const int tid = blockIdx.x * BLOCK + t;
    const int stride = GRID * BLOCK;
    const float2* __restrict__ in2 = (const float2*)inputs;
    (void)npts;   // npts == GRID*BLOCK*16 exactly -> no bounds checks

    // ---- input prefetch issued before staging (R5; cold-HBM overlap) ----
    float2 a0 = in2[tid];
    float2 a1 = in2[tid + stride];
    float2 a2 = in2[tid + 2 * stride];
    float2 b0 = in2[tid + OUTER * stride];
    float2 b1 = in2[tid + (OUTER + 1) * stride];
    float2 b2 = in2[tid + (OUTER + 2) * stride];

    // ---- MAIN: 256 rows x 64 quads == 16 x 1024 tasks exactly, no tails ----
    // stored value = coe * s(row&3) * s(col&3), s = [1/24, -1/6, 1/4, -1/6]
#pragma unroll
    for (int k = 0; k < 16; ++k) {
        int g = t + k * BLOCK;
        int r = g >> 6;                 // 0..255
        int c4 = (g & 63) << 2;         // 0..252
        f4u q = *(const f4u*)(coe + r * NGRID + c4);
        float rs = rowscale(r);
        half4_t h = { (_Float16)(q.x * (rs * (1.0f / 24.0f))),
                      (_Float16)(q.y * (rs * (-1.0f / 6.0f))),
                      (_Float16)(q.z * (rs * 0.25f)),
                      (_Float16)(q.w * (rs * (-1.0f / 6.0f))) };
        *(half4_t*)(lds + (r << 8) + c4) = h;
    }
    // ---- S1: row 256 (rowscale 1/24), cols 0..255 ----
    if (t < 64) {
        int c4 = t << 2;
        f4u q = *(const f4u*)(coe + 256 * NGRID + c4);
        const float rs = 1.0f / 24.0f;
        half4_t h = { (_Float16)(q.x * (rs * (1.0f / 24.0f))),
                      (_Float16)(q.y * (rs * (-1.0f / 6.0f))),
                      (_Float16)(q.z * (rs * 0.25f)),
                      (_Float16)(q.w * (rs * (-1.0f / 6.0f))) };
        *(half4_t*)(lds + OFF1_H + c4) = h;
    }
    // ---- T: 8000 dwords == 7 x 1024 + 832 tasks. task = (d, c1):
    //      T[c1][d] = pack(coe[2d][4c1+4], coe[2d+1][4c1+4]) * scales ----
#pragma unroll
    for (int j = 0; j < 8; ++j) {
        int idx = t + j * BLOCK;
        if (idx < 8000) {
            int c1 = idx & 63;
            int d  = idx >> 6;          // 0..124
            const float* src = coe + (2 * d) * NGRID + 4 * c1 + 4;
            float va = src[0];
            float vb = src[NGRID];
            float rsa = (d & 1) ? 0.25f : (1.0f / 24.0f);   // rowscale(2d)
            va *= rsa * (1.0f / 24.0f);                     // colscale(col%4==0)
            vb *= (-1.0f / 6.0f) * (1.0f / 24.0f);          // rowscale(2d+1)
            ((unsigned*)lds)[T_DW + 125 * c1 + d] =
                __builtin_bit_cast(unsigned, pack2(va, vb));
        }
    }
    // ---- S2: col 256 (colscale 1/24), rows 248..256 ----
    if (t < 9) {
        int r = 248 + t;
        lds[S2_H + t] = (_Float16)(coe[r * NGRID + 256] * (rowscale(r) * (1.0f / 24.0f)));
    }
    __syncthreads();

    // Two point streams (k and k+OUTER), 3-deep input prefetch each.
#pragma unroll
    for (int k = 0; k < OUTER; ++k) {
        float2 a3, b3;
        if (k + 3 < OUTER) {
            a3 = in2[tid + (k + 3) * stride];
            b3 = in2[tid + (k + OUTER + 3) * stride];
        }
        float ra = eval_pt(lds, a0.x, a0.y);
        float rb = eval_pt(lds, b0.x, b0.y);
        __builtin_nontemporal_store(ra, &out[tid + k * stride]);
        __builtin_nontemporal_store(rb, &out[tid + (k + OUTER) * stride]);
        a0 = a1; a1 = a2; a2 = a3;
        b0 = b1; b1 = b2; b2 = b3;
    }
}

extern "C" void kernel_launch(void* const* d_in, const int* in_sizes, int n_in,
                              void* d_out, int out_size, void* d_ws, size_t ws_size,
                              hipStream_t stream) {
    const float* inputs = (const float*)d_in[0];   // (2048,2048,2) f32
    const float* coe    = (const float*)d_in[1];   // (257,257) f32
    float* out = (float*)d_out;                    // (2048,2048) f32
    int npts = out_size;                           // 4,194,304

    (void)hipFuncSetAttribute((const void*)lagrange_kernel,
                              hipFuncAttributeMaxDynamicSharedMemorySize,
                              LDS_BYTES);

    dim3 grid(GRID), block(BLOCK);   // 1 block/CU (LDS-limited), 16 waves/CU
    hipLaunchKernelGGL(lagrange_kernel, grid, block, LDS_BYTES, stream,
                       inputs, coe, out, npts);
}